// Round 4
// baseline (807.077 us; speedup 1.0000x reference)
//
#include <hip/hip_runtime.h>

#define NB 512
#define NT 1024
#define NK 48
#define NEGV -10000.0f
#define S_START 46
#define S_END 47
#define NCH 64            // chunks per sequence
#define CLEN 16           // steps per chunk (NCH*CLEN == NT)

// ---- workspace layout (bytes) ----
#define WS_CKPT 0                                   // f32 [NB][NCH][NK] chunk-entry v
#define WS_CKPT_SZ (NB * NCH * NK * 4)
#define WS_LAST (WS_CKPT + WS_CKPT_SZ)              // i32 [NB] termination tag
#define WS_LAST_SZ (NB * 4)
#define WS_COMP (WS_LAST + WS_LAST_SZ)              // u8 [NB][NCH][NK] composed maps
#define WS_COMP_SZ (NB * NCH * NK)
#define WS_BP (WS_COMP + WS_COMP_SZ)                // u8 [NB][NCH][CLEN][NK] backptrs
#define WS_BP_SZ (NB * NCH * CLEN * NK)
#define WS_NEED (WS_BP + WS_BP_SZ)                  // 33,032,192 B

__device__ __forceinline__ float rfl_f32(float x) {
    return __int_as_float(__builtin_amdgcn_readfirstlane(__float_as_int(x)));
}

// =====================================================================
// Kernel A: 2 sequences per wave. wave 0: forward logZ for seqs b0,b1;
// wave 1: value-only Viterbi sweep + checkpoints for seqs b0,b1.
// LDS broadcast (proven structure); dual chains hide the LDS round-trip
// latency behind the other chain's VALU work. Erow/trow shared.
// =====================================================================
extern "C" __global__ __launch_bounds__(128, 1)
void crf_sweep(const float* __restrict__ feats, const float* __restrict__ trans,
               float* __restrict__ out, unsigned char* __restrict__ ws)
{
    __shared__ __align__(16) float eabufA[64];
    __shared__ __align__(16) float eabufB[64];
    __shared__ __align__(16) float vbufA[64];
    __shared__ __align__(16) float vbufB[64];

    const int b0 = blockIdx.x * 2;
    const int b1 = b0 + 1;
    const int wave = threadIdx.x >> 6;
    const int lane = threadIdx.x & 63;
    const bool act = lane < NK;
    const int LL = act ? lane : (NK - 1);        // clamped: lanes 48..63 mirror 47
    const float* fbA = feats + (size_t)b0 * NT * NK + LL;
    const float* fbB = feats + (size_t)b1 * NT * NK + LL;

    float tEnd = NEGV;
    if (act && lane != S_END) tEnd = trans[S_END * NK + lane];

    if (wave == 0) {
        // ---------------- forward: alpha' = Muni + u; u anchored at lane 0
        float Erow[NK];
        {
            const bool rowdead = (lane == S_START);
            const float4* r4 = (const float4*)(trans + LL * NK);
            #pragma unroll
            for (int q = 0; q < NK / 4; ++q) {
                float4 r = r4[q];
                const int c = 4 * q;
                Erow[c + 0] = (rowdead || c + 0 == S_END) ? 0.0f : __expf(r.x);
                Erow[c + 1] = (rowdead || c + 1 == S_END) ? 0.0f : __expf(r.y);
                Erow[c + 2] = (rowdead || c + 2 == S_END) ? 0.0f : __expf(r.z);
                Erow[c + 3] = (rowdead || c + 3 == S_END) ? 0.0f : __expf(r.w);
            }
        }
        float uA = (lane == S_START) ? 0.0f : NEGV;
        float uB = uA;
        float MuniA = 0.0f, MuniB = 0.0f;
        eabufA[lane] = __expf(uA);
        eabufB[lane] = __expf(uB);
        __builtin_amdgcn_wave_barrier();

        float frA0 = fbA[0 * NK], frA1 = fbA[1 * NK], frA2 = fbA[2 * NK], frA3 = fbA[3 * NK];
        float frB0 = fbB[0 * NK], frB1 = fbB[1 * NK], frB2 = fbB[2 * NK], frB3 = fbB[3 * NK];

        auto fstep2 = [&](float fcA, float fcB) {
            float eaA[NK], eaB[NK];
            {
                const float4* e4 = (const float4*)eabufA;
                #pragma unroll
                for (int q = 0; q < NK / 4; ++q) {
                    float4 r = e4[q];
                    eaA[4 * q + 0] = r.x; eaA[4 * q + 1] = r.y;
                    eaA[4 * q + 2] = r.z; eaA[4 * q + 3] = r.w;
                }
            }
            {
                const float4* e4 = (const float4*)eabufB;
                #pragma unroll
                for (int q = 0; q < NK / 4; ++q) {
                    float4 r = e4[q];
                    eaB[4 * q + 0] = r.x; eaB[4 * q + 1] = r.y;
                    eaB[4 * q + 2] = r.z; eaB[4 * q + 3] = r.w;
                }
            }
            // chain A (B's reads still in flight -> latency hidden)
            float a0 = 0.f, a1 = 0.f, a2 = 0.f, a3 = 0.f;
            #pragma unroll
            for (int p = 0; p < NK; p += 4) {
                a0 = fmaf(Erow[p + 0], eaA[p + 0], a0);
                a1 = fmaf(Erow[p + 1], eaA[p + 1], a1);
                a2 = fmaf(Erow[p + 2], eaA[p + 2], a2);
                a3 = fmaf(Erow[p + 3], eaA[p + 3], a3);
            }
            float accA = (a0 + a1) + (a2 + a3);
            float wA = __logf(accA) + fcA;
            float dMA = rfl_f32(wA);
            MuniA += dMA;
            uA = wA - dMA;
            float eA = __expf(uA);
            // chain B
            float c0 = 0.f, c1 = 0.f, c2 = 0.f, c3 = 0.f;
            #pragma unroll
            for (int p = 0; p < NK; p += 4) {
                c0 = fmaf(Erow[p + 0], eaB[p + 0], c0);
                c1 = fmaf(Erow[p + 1], eaB[p + 1], c1);
                c2 = fmaf(Erow[p + 2], eaB[p + 2], c2);
                c3 = fmaf(Erow[p + 3], eaB[p + 3], c3);
            }
            float accB = (c0 + c1) + (c2 + c3);
            float wB = __logf(accB) + fcB;
            float dMB = rfl_f32(wB);
            MuniB += dMB;
            uB = wB - dMB;
            float eB = __expf(uB);
            __builtin_amdgcn_wave_barrier();
            eabufA[lane] = eA;
            eabufB[lane] = eB;
            __builtin_amdgcn_wave_barrier();
        };

        for (int t = 0; t < NT; t += 4) {
            { float fA = frA0, fB = frB0; int nr = (t + 4 < NT) ? t + 4 : NT - 1;
              frA0 = fbA[nr * NK]; frB0 = fbB[nr * NK]; fstep2(fA, fB); }
            { float fA = frA1, fB = frB1; int nr = (t + 5 < NT) ? t + 5 : NT - 1;
              frA1 = fbA[nr * NK]; frB1 = fbB[nr * NK]; fstep2(fA, fB); }
            { float fA = frA2, fB = frB2; int nr = (t + 6 < NT) ? t + 6 : NT - 1;
              frA2 = fbA[nr * NK]; frB2 = fbB[nr * NK]; fstep2(fA, fB); }
            { float fA = frA3, fB = frB3; int nr = (t + 7 < NT) ? t + 7 : NT - 1;
              frA3 = fbA[nr * NK]; frB3 = fbB[nr * NK]; fstep2(fA, fB); }
        }
        // logz epilogue, chain A
        {
            float x = act ? (uA + tEnd) : -INFINITY;
            float M2 = x;
            #pragma unroll
            for (int off = 32; off >= 1; off >>= 1)
                M2 = fmaxf(M2, __shfl_xor(M2, off, 64));
            float e = __expf(x - M2);
            #pragma unroll
            for (int off = 32; off >= 1; off >>= 1)
                e += __shfl_xor(e, off, 64);
            if (lane == 0) out[b0] = MuniA + M2 + __logf(e);
        }
        // chain B
        {
            float x = act ? (uB + tEnd) : -INFINITY;
            float M2 = x;
            #pragma unroll
            for (int off = 32; off >= 1; off >>= 1)
                M2 = fmaxf(M2, __shfl_xor(M2, off, 64));
            float e = __expf(x - M2);
            #pragma unroll
            for (int off = 32; off >= 1; off >>= 1)
                e += __shfl_xor(e, off, 64);
            if (lane == 0) out[b1] = MuniB + M2 + __logf(e);
        }
    } else {
        // ---------------- viterbi value-only sweep, 2 chains; ckpt every CLEN
        float trow[NK];
        {
            const bool rowdead = (lane == S_START);
            const float4* r4 = (const float4*)(trans + LL * NK);
            #pragma unroll
            for (int q = 0; q < NK / 4; ++q) {
                float4 r = r4[q];
                const int c = 4 * q;
                trow[c + 0] = (rowdead || c + 0 == S_END) ? NEGV : r.x;
                trow[c + 1] = (rowdead || c + 1 == S_END) ? NEGV : r.y;
                trow[c + 2] = (rowdead || c + 2 == S_END) ? NEGV : r.z;
                trow[c + 3] = (rowdead || c + 3 == S_END) ? NEGV : r.w;
            }
        }
        float vA = (lane == S_START) ? 0.0f : NEGV;
        float vB = vA;
        vbufA[lane] = vA;
        vbufB[lane] = vB;
        __builtin_amdgcn_wave_barrier();
        float* ckptA = (float*)(ws + WS_CKPT) + (size_t)b0 * NCH * NK;
        float* ckptB = (float*)(ws + WS_CKPT) + (size_t)b1 * NCH * NK;
        if (act) { ckptA[lane] = vA; ckptB[lane] = vB; }

        float frA0 = fbA[0 * NK], frA1 = fbA[1 * NK], frA2 = fbA[2 * NK], frA3 = fbA[3 * NK];
        float frB0 = fbB[0 * NK], frB1 = fbB[1 * NK], frB2 = fbB[2 * NK], frB3 = fbB[3 * NK];

        // exact max via tree (max exactly associative; identical to np.max)
        auto maxtree = [&](const float* s) -> float {
            float m16[16];
            #pragma unroll
            for (int i = 0; i < 16; ++i)
                m16[i] = fmaxf(fmaxf(s[3 * i], s[3 * i + 1]), s[3 * i + 2]);
            float m6[6];
            #pragma unroll
            for (int i = 0; i < 5; ++i)
                m6[i] = fmaxf(fmaxf(m16[3 * i], m16[3 * i + 1]), m16[3 * i + 2]);
            m6[5] = m16[15];
            return fmaxf(fmaxf(fmaxf(m6[0], m6[1]), m6[2]),
                         fmaxf(fmaxf(m6[3], m6[4]), m6[5]));
        };

        auto vstep2 = [&](float fcA, float fcB, int tt) {
            float sA[NK], sB[NK];
            {
                const float4* v4 = (const float4*)vbufA;
                #pragma unroll
                for (int q = 0; q < NK / 4; ++q) {
                    float4 r = v4[q];
                    sA[4 * q + 0] = r.x + trow[4 * q + 0];
                    sA[4 * q + 1] = r.y + trow[4 * q + 1];
                    sA[4 * q + 2] = r.z + trow[4 * q + 2];
                    sA[4 * q + 3] = r.w + trow[4 * q + 3];
                }
            }
            {
                const float4* v4 = (const float4*)vbufB;
                #pragma unroll
                for (int q = 0; q < NK / 4; ++q) {
                    float4 r = v4[q];
                    sB[4 * q + 0] = r.x + trow[4 * q + 0];
                    sB[4 * q + 1] = r.y + trow[4 * q + 1];
                    sB[4 * q + 2] = r.z + trow[4 * q + 2];
                    sB[4 * q + 3] = r.w + trow[4 * q + 3];
                }
            }
            float bestA = maxtree(sA);
            vA = bestA + fcA;                    // reference order: +feat after max
            float bestB = maxtree(sB);
            vB = bestB + fcB;
            __builtin_amdgcn_wave_barrier();
            vbufA[lane] = vA;
            vbufB[lane] = vB;
            __builtin_amdgcn_wave_barrier();
            if (((tt + 1) & (CLEN - 1)) == 0 && (tt + 1) < NT && act) {
                ckptA[((tt + 1) >> 4) * NK + lane] = vA;
                ckptB[((tt + 1) >> 4) * NK + lane] = vB;
            }
        };

        for (int t = 0; t < NT; t += 4) {
            { float fA = frA0, fB = frB0; int nr = (t + 4 < NT) ? t + 4 : NT - 1;
              frA0 = fbA[nr * NK]; frB0 = fbB[nr * NK]; vstep2(fA, fB, t + 0); }
            { float fA = frA1, fB = frB1; int nr = (t + 5 < NT) ? t + 5 : NT - 1;
              frA1 = fbA[nr * NK]; frB1 = fbB[nr * NK]; vstep2(fA, fB, t + 1); }
            { float fA = frA2, fB = frB2; int nr = (t + 6 < NT) ? t + 6 : NT - 1;
              frA2 = fbA[nr * NK]; frB2 = fbB[nr * NK]; vstep2(fA, fB, t + 2); }
            { float fA = frA3, fB = frB3; int nr = (t + 7 < NT) ? t + 7 : NT - 1;
              frA3 = fbA[nr * NK]; frB3 = fbB[nr * NK]; vstep2(fA, fB, t + 3); }
        }
        // termination: first-occurrence argmax of v + trans[END], per chain
        {
            float xv = act ? (vA + tEnd) : -INFINITY;
            int idx = act ? lane : 63;
            float val = xv;
            #pragma unroll
            for (int off = 32; off >= 1; off >>= 1) {
                float ov = __shfl_xor(val, off, 64);
                int   oi = __shfl_xor(idx, off, 64);
                if (ov > val || (ov == val && oi < idx)) { val = ov; idx = oi; }
            }
            if (lane == 0) {
                out[NB + b0] = val;
                ((int*)(ws + WS_LAST))[b0] = idx;
            }
        }
        {
            float xv = act ? (vB + tEnd) : -INFINITY;
            int idx = act ? lane : 63;
            float val = xv;
            #pragma unroll
            for (int off = 32; off >= 1; off >>= 1) {
                float ov = __shfl_xor(val, off, 64);
                int   oi = __shfl_xor(idx, off, 64);
                if (ov > val || (ov == val && oi < idx)) { val = ov; idx = oi; }
            }
            if (lane == 0) {
                out[NB + b1] = val;
                ((int*)(ws + WS_LAST))[b1] = idx;
            }
        }
    }
}

// =====================================================================
// Kernel B (round-2 proven form): parallel chunk replay. Each wave
// re-runs one 16-step chunk from its checkpoint with the FULL original
// vstep (identical arithmetic -> identical backpointers), emits bp +
// composed chunk tag-map.
// =====================================================================
extern "C" __global__ void
crf_chunks(const float* __restrict__ feats, const float* __restrict__ trans,
           unsigned char* __restrict__ ws)
{
    __shared__ float vbuf[64];
    __shared__ unsigned char bp16[CLEN * NK];

    const int b = blockIdx.x;
    const int c = blockIdx.y;
    const int lane = threadIdx.x & 63;
    const bool act = lane < NK;
    const int LL = act ? lane : (NK - 1);

    float trow[NK];
    {
        const bool rowdead = (lane == S_START);
        const float4* r4 = (const float4*)(trans + LL * NK);
        #pragma unroll
        for (int q = 0; q < NK / 4; ++q) {
            float4 r = r4[q];
            const int cc = 4 * q;
            trow[cc + 0] = (rowdead || cc + 0 == S_END) ? NEGV : r.x;
            trow[cc + 1] = (rowdead || cc + 1 == S_END) ? NEGV : r.y;
            trow[cc + 2] = (rowdead || cc + 2 == S_END) ? NEGV : r.z;
            trow[cc + 3] = (rowdead || cc + 3 == S_END) ? NEGV : r.w;
        }
    }
    const float* ckpt = (const float*)(ws + WS_CKPT) + ((size_t)b * NCH + c) * NK;
    if (act) vbuf[lane] = ckpt[lane];
    __builtin_amdgcn_wave_barrier();

    const float* fb = feats + (size_t)b * NT * NK + (size_t)c * CLEN * NK + LL;
    const int big = 63;

    float fr0 = fb[0 * NK], fr1 = fb[1 * NK], fr2 = fb[2 * NK], fr3 = fb[3 * NK];

    auto vstepB = [&](float fc, int tt) {
        float s[NK];
        {
            const float4* v4 = (const float4*)vbuf;
            #pragma unroll
            for (int q = 0; q < NK / 4; ++q) {
                float4 r = v4[q];
                s[4 * q + 0] = r.x + trow[4 * q + 0];
                s[4 * q + 1] = r.y + trow[4 * q + 1];
                s[4 * q + 2] = r.z + trow[4 * q + 2];
                s[4 * q + 3] = r.w + trow[4 * q + 3];
            }
        }
        float m16[16];
        #pragma unroll
        for (int i = 0; i < 16; ++i)
            m16[i] = fmaxf(fmaxf(s[3 * i], s[3 * i + 1]), s[3 * i + 2]);
        float m6[6];
        #pragma unroll
        for (int i = 0; i < 5; ++i)
            m6[i] = fmaxf(fmaxf(m16[3 * i], m16[3 * i + 1]), m16[3 * i + 2]);
        m6[5] = m16[15];
        float best = fmaxf(fmaxf(fmaxf(m6[0], m6[1]), m6[2]),
                           fmaxf(fmaxf(m6[3], m6[4]), m6[5]));
        int ix[NK];
        #pragma unroll
        for (int p = 0; p < NK; ++p)
            ix[p] = (s[p] != best) ? big : p;
        int n16[16];
        #pragma unroll
        for (int i = 0; i < 16; ++i)
            n16[i] = min(min(ix[3 * i], ix[3 * i + 1]), ix[3 * i + 2]);
        int n6[6];
        #pragma unroll
        for (int i = 0; i < 5; ++i)
            n6[i] = min(min(n16[3 * i], n16[3 * i + 1]), n16[3 * i + 2]);
        n6[5] = n16[15];
        int bi = min(min(min(n6[0], n6[1]), n6[2]),
                     min(min(n6[3], n6[4]), n6[5]));

        bp16[tt * NK + LL] = (unsigned char)bi;
        float v = best + fc;
        __builtin_amdgcn_wave_barrier();
        vbuf[lane] = v;
        __builtin_amdgcn_wave_barrier();
    };

    for (int t = 0; t < CLEN; t += 4) {
        { float fc = fr0; int nr = (t + 4 < CLEN) ? t + 4 : CLEN - 1; fr0 = fb[nr * NK]; vstepB(fc, t + 0); }
        { float fc = fr1; int nr = (t + 5 < CLEN) ? t + 5 : CLEN - 1; fr1 = fb[nr * NK]; vstepB(fc, t + 1); }
        { float fc = fr2; int nr = (t + 6 < CLEN) ? t + 6 : CLEN - 1; fr2 = fb[nr * NK]; vstepB(fc, t + 2); }
        { float fc = fr3; int nr = (t + 7 < CLEN) ? t + 7 : CLEN - 1; fr3 = fb[nr * NK]; vstepB(fc, t + 3); }
    }
    __builtin_amdgcn_wave_barrier();

    // dump raw backpointers for this chunk (768 B, coalesced dwords)
    {
        unsigned int* dst = (unsigned int*)(ws + WS_BP) + ((size_t)b * NCH + c) * (CLEN * NK / 4);
        const unsigned int* src = (const unsigned int*)bp16;
        for (int j = lane; j < CLEN * NK / 4; j += 64) dst[j] = src[j];
    }
    // composed chunk tag-map: end-tag k -> tag at chunk entry
    if (act) {
        int tag = lane;
        #pragma unroll
        for (int i = CLEN - 1; i >= 0; --i) tag = bp16[i * NK + tag];
        (ws + WS_COMP)[((size_t)b * NCH + c) * NK + lane] = (unsigned char)tag;
    }
}

// =====================================================================
// Kernel C: per-sequence boundary chase over composed maps + per-chunk
// path expansion from global backpointers.
// =====================================================================
extern "C" __global__ __launch_bounds__(64, 1)
void crf_trace(float* __restrict__ out, unsigned char* __restrict__ ws)
{
    __shared__ unsigned char compL[NCH * NK];    // 3 KB
    __shared__ unsigned char boundary[NCH];

    const int b = blockIdx.x;
    const int lane = threadIdx.x & 63;

    {
        const unsigned int* src = (const unsigned int*)(ws + WS_COMP) + (size_t)b * (NCH * NK / 4);
        unsigned int* dst = (unsigned int*)compL;
        for (int j = lane; j < NCH * NK / 4; j += 64) dst[j] = src[j];
    }
    __builtin_amdgcn_wave_barrier();

    if (lane == 0) {                             // serial chase over 64 maps
        int tag = ((const int*)(ws + WS_LAST))[b];
        for (int l = NCH - 1; l >= 0; --l) {
            boundary[l] = (unsigned char)tag;
            tag = compL[l * NK + tag];
        }
    }
    __builtin_amdgcn_wave_barrier();

    int tag = boundary[lane];                    // lane = chunk index
    const unsigned char* bpc = (ws + WS_BP) + ((size_t)b * NCH + lane) * (CLEN * NK);
    float* pout = out + 2 * NB + (size_t)b * NT + lane * CLEN;
    #pragma unroll
    for (int i = CLEN - 1; i >= 0; --i) {
        pout[i] = (float)tag;
        tag = bpc[i * NK + tag];
    }
}

// =====================================================================
// Fallback: proven single-kernel version (used if workspace too small).
// =====================================================================
extern "C" __global__ __launch_bounds__(128, 1)
void crf_fused(const float* __restrict__ feats, const float* __restrict__ trans,
               float* __restrict__ out)
{
    __shared__ unsigned char bp[NT * NK];
    __shared__ unsigned char comp[64 * NK];
    __shared__ unsigned char boundary[64];
    __shared__ float eabuf[64];
    __shared__ float vbuf[64];

    const int b = blockIdx.x;
    const int wave = threadIdx.x >> 6;
    const int lane = threadIdx.x & 63;
    const bool act = lane < NK;
    const int LL = act ? lane : (NK - 1);
    const float* f = feats + (size_t)b * NT * NK;
    const float* fb = f + LL;

    float tEnd = NEGV;
    if (act && lane != S_END) tEnd = trans[S_END * NK + lane];

    if (wave == 0) {
        float Erow[NK];
        {
            const bool rowdead = (lane == S_START);
            const float4* r4 = (const float4*)(trans + LL * NK);
            #pragma unroll
            for (int q = 0; q < NK / 4; ++q) {
                float4 r = r4[q];
                const int c = 4 * q;
                Erow[c + 0] = (rowdead || c + 0 == S_END) ? 0.0f : __expf(r.x);
                Erow[c + 1] = (rowdead || c + 1 == S_END) ? 0.0f : __expf(r.y);
                Erow[c + 2] = (rowdead || c + 2 == S_END) ? 0.0f : __expf(r.z);
                Erow[c + 3] = (rowdead || c + 3 == S_END) ? 0.0f : __expf(r.w);
            }
        }
        float u = (lane == S_START) ? 0.0f : NEGV;
        float Muni = 0.0f;
        eabuf[lane] = __expf(u);
        __builtin_amdgcn_wave_barrier();

        float fr0 = fb[0 * NK], fr1 = fb[1 * NK], fr2 = fb[2 * NK], fr3 = fb[3 * NK];

        auto fstep = [&](float fc) {
            float ea[NK];
            {
                const float4* e4 = (const float4*)eabuf;
                #pragma unroll
                for (int q = 0; q < NK / 4; ++q) {
                    float4 r = e4[q];
                    ea[4 * q + 0] = r.x; ea[4 * q + 1] = r.y;
                    ea[4 * q + 2] = r.z; ea[4 * q + 3] = r.w;
                }
            }
            float a0 = 0.f, a1 = 0.f, a2 = 0.f, a3 = 0.f;
            #pragma unroll
            for (int p = 0; p < NK; p += 4) {
                a0 = fmaf(Erow[p + 0], ea[p + 0], a0);
                a1 = fmaf(Erow[p + 1], ea[p + 1], a1);
                a2 = fmaf(Erow[p + 2], ea[p + 2], a2);
                a3 = fmaf(Erow[p + 3], ea[p + 3], a3);
            }
            float acc = (a0 + a1) + (a2 + a3);
            float w = __logf(acc) + fc;
            float dM = rfl_f32(w);
            Muni += dM;
            u = w - dM;
            __builtin_amdgcn_wave_barrier();
            eabuf[lane] = __expf(u);
            __builtin_amdgcn_wave_barrier();
        };

        for (int t = 0; t < NT; t += 4) {
            { float fc = fr0; int nr = (t + 4 < NT) ? t + 4 : NT - 1; fr0 = fb[nr * NK]; fstep(fc); }
            { float fc = fr1; int nr = (t + 5 < NT) ? t + 5 : NT - 1; fr1 = fb[nr * NK]; fstep(fc); }
            { float fc = fr2; int nr = (t + 6 < NT) ? t + 6 : NT - 1; fr2 = fb[nr * NK]; fstep(fc); }
            { float fc = fr3; int nr = (t + 7 < NT) ? t + 7 : NT - 1; fr3 = fb[nr * NK]; fstep(fc); }
        }
        float x = act ? (u + tEnd) : -INFINITY;
        float M2 = x;
        #pragma unroll
        for (int off = 32; off >= 1; off >>= 1)
            M2 = fmaxf(M2, __shfl_xor(M2, off, 64));
        float e = __expf(x - M2);
        #pragma unroll
        for (int off = 32; off >= 1; off >>= 1)
            e += __shfl_xor(e, off, 64);
        if (lane == 0) out[b] = Muni + M2 + __logf(e);
    } else {
        float trow[NK];
        {
            const bool rowdead = (lane == S_START);
            const float4* r4 = (const float4*)(trans + LL * NK);
            #pragma unroll
            for (int q = 0; q < NK / 4; ++q) {
                float4 r = r4[q];
                const int c = 4 * q;
                trow[c + 0] = (rowdead || c + 0 == S_END) ? NEGV : r.x;
                trow[c + 1] = (rowdead || c + 1 == S_END) ? NEGV : r.y;
                trow[c + 2] = (rowdead || c + 2 == S_END) ? NEGV : r.z;
                trow[c + 3] = (rowdead || c + 3 == S_END) ? NEGV : r.w;
            }
        }
        float v = (lane == S_START) ? 0.0f : NEGV;
        vbuf[lane] = v;
        __builtin_amdgcn_wave_barrier();

        float fr0 = fb[0 * NK], fr1 = fb[1 * NK], fr2 = fb[2 * NK], fr3 = fb[3 * NK];
        const int big = 63;

        auto vstep = [&](float fc, int tt) {
            float s[NK];
            {
                const float4* v4 = (const float4*)vbuf;
                #pragma unroll
                for (int q = 0; q < NK / 4; ++q) {
                    float4 r = v4[q];
                    s[4 * q + 0] = r.x + trow[4 * q + 0];
                    s[4 * q + 1] = r.y + trow[4 * q + 1];
                    s[4 * q + 2] = r.z + trow[4 * q + 2];
                    s[4 * q + 3] = r.w + trow[4 * q + 3];
                }
            }
            float m16[16];
            #pragma unroll
            for (int i = 0; i < 16; ++i)
                m16[i] = fmaxf(fmaxf(s[3 * i], s[3 * i + 1]), s[3 * i + 2]);
            float m6[6];
            #pragma unroll
            for (int i = 0; i < 5; ++i)
                m6[i] = fmaxf(fmaxf(m16[3 * i], m16[3 * i + 1]), m16[3 * i + 2]);
            m6[5] = m16[15];
            float best = fmaxf(fmaxf(fmaxf(m6[0], m6[1]), m6[2]),
                               fmaxf(fmaxf(m6[3], m6[4]), m6[5]));
            int ix[NK];
            #pragma unroll
            for (int p = 0; p < NK; ++p)
                ix[p] = (s[p] != best) ? big : p;
            int n16[16];
            #pragma unroll
            for (int i = 0; i < 16; ++i)
                n16[i] = min(min(ix[3 * i], ix[3 * i + 1]), ix[3 * i + 2]);
            int n6[6];
            #pragma unroll
            for (int i = 0; i < 5; ++i)
                n6[i] = min(min(n16[3 * i], n16[3 * i + 1]), n16[3 * i + 2]);
            n6[5] = n16[15];
            int bi = min(min(min(n6[0], n6[1]), n6[2]),
                         min(min(n6[3], n6[4]), n6[5]));

            bp[tt * NK + LL] = (unsigned char)bi;
            v = best + fc;
            __builtin_amdgcn_wave_barrier();
            vbuf[lane] = v;
            __builtin_amdgcn_wave_barrier();
        };

        for (int t = 0; t < NT; t += 4) {
            { float fc = fr0; int nr = (t + 4 < NT) ? t + 4 : NT - 1; fr0 = fb[nr * NK]; vstep(fc, t + 0); }
            { float fc = fr1; int nr = (t + 5 < NT) ? t + 5 : NT - 1; fr1 = fb[nr * NK]; vstep(fc, t + 1); }
            { float fc = fr2; int nr = (t + 6 < NT) ? t + 6 : NT - 1; fr2 = fb[nr * NK]; vstep(fc, t + 2); }
            { float fc = fr3; int nr = (t + 7 < NT) ? t + 7 : NT - 1; fr3 = fb[nr * NK]; vstep(fc, t + 3); }
        }
        float xv = act ? (v + tEnd) : -INFINITY;
        int idx = act ? lane : 63;
        float val = xv;
        #pragma unroll
        for (int off = 32; off >= 1; off >>= 1) {
            float ov = __shfl_xor(val, off, 64);
            int   oi = __shfl_xor(idx, off, 64);
            if (ov > val || (ov == val && oi < idx)) { val = ov; idx = oi; }
        }
        if (lane == 0) out[NB + b] = val;
        const int last = idx;

        __builtin_amdgcn_wave_barrier();
        int cur[NK];
        #pragma unroll
        for (int k = 0; k < NK; ++k) cur[k] = k;
        const int tbase = lane * 16;
        for (int i = 15; i >= 0; --i) {
            const int t = tbase + i;
            #pragma unroll
            for (int k = 0; k < NK; ++k) cur[k] = bp[t * NK + cur[k]];
        }
        #pragma unroll
        for (int k = 0; k < NK; ++k) comp[lane * NK + k] = (unsigned char)cur[k];
        __builtin_amdgcn_wave_barrier();

        if (lane == 0) {
            int tag = last;
            for (int l = 63; l >= 0; --l) {
                boundary[l] = (unsigned char)tag;
                tag = comp[l * NK + tag];
            }
        }
        __builtin_amdgcn_wave_barrier();

        int tag = boundary[lane];
        float* pout = out + 2 * NB + (size_t)b * NT;
        for (int i = 15; i >= 0; --i) {
            const int t = tbase + i;
            pout[t] = (float)tag;
            tag = bp[t * NK + tag];
        }
    }
}

extern "C" void kernel_launch(void* const* d_in, const int* in_sizes, int n_in,
                              void* d_out, int out_size, void* d_ws, size_t ws_size,
                              hipStream_t stream) {
    (void)in_sizes; (void)n_in; (void)out_size;
    const float* feats = (const float*)d_in[0];
    const float* trans = (const float*)d_in[1];
    float* out = (float*)d_out;
    if (d_ws != nullptr && ws_size >= (size_t)WS_NEED) {
        unsigned char* ws = (unsigned char*)d_ws;
        crf_sweep<<<dim3(NB / 2), dim3(128), 0, stream>>>(feats, trans, out, ws);
        crf_chunks<<<dim3(NB, NCH), dim3(64), 0, stream>>>(feats, trans, ws);
        crf_trace<<<dim3(NB), dim3(64), 0, stream>>>(out, ws);
    } else {
        crf_fused<<<dim3(NB), dim3(128), 0, stream>>>(feats, trans, out);
    }
}

// Round 5
// 528.382 us; speedup vs baseline: 1.5275x; 1.5275x over previous
//
#include <hip/hip_runtime.h>

#define NB 512
#define NT 1024
#define NK 48
#define NEGV -10000.0f
#define S_START 46
#define S_END 47

__device__ __forceinline__ float rfl_f32(float x) {
    return __int_as_float(__builtin_amdgcn_readfirstlane(__float_as_int(x)));
}

extern "C" __global__ __launch_bounds__(128, 1)
void crf_fused(const float* __restrict__ feats, const float* __restrict__ trans,
               float* __restrict__ out)
{
    // wave 0: CRF forward (logZ).  wave 1: Viterbi + backtrace.
    // All LDS traffic intra-wave (DS pipe in-order per wave): no s_barrier.
    __shared__ unsigned char bp[NT * NK];        // 48 KB backpointers (wave 1)
    __shared__ unsigned char comp[64 * NK];      // composed chunk tag-maps
    __shared__ unsigned char boundary[64];       // chunk-entry tags
    __shared__ float eabuf[64];                  // forward broadcast buffer
    __shared__ float vbuf[64];                   // viterbi broadcast buffer

    const int b = blockIdx.x;
    const int wave = threadIdx.x >> 6;
    const int lane = threadIdx.x & 63;
    const bool act = lane < NK;
    const int LL = act ? lane : (NK - 1);        // clamped state: lanes 48..63 mirror 47
    const float* f = feats + (size_t)b * NT * NK;
    const float* fb = f + LL;                    // per-lane column base (always in-bounds)

    float tEnd = NEGV;
    if (act && lane != S_END) tEnd = trans[S_END * NK + lane];

    if (wave == 0) {
        // ---------------- forward: alpha' = Muni + u;  u anchored at lane 0 (u[0]==0)
        float Erow[NK];
        {
            const bool rowdead = (lane == S_START);
            const float4* r4 = (const float4*)(trans + LL * NK);
            #pragma unroll
            for (int q = 0; q < NK / 4; ++q) {
                float4 r = r4[q];
                const int c = 4 * q;
                Erow[c + 0] = (rowdead || c + 0 == S_END) ? 0.0f : __expf(r.x);
                Erow[c + 1] = (rowdead || c + 1 == S_END) ? 0.0f : __expf(r.y);
                Erow[c + 2] = (rowdead || c + 2 == S_END) ? 0.0f : __expf(r.z);
                Erow[c + 3] = (rowdead || c + 3 == S_END) ? 0.0f : __expf(r.w);
            }
        }
        float u = (lane == S_START) ? 0.0f : NEGV;
        float Muni = 0.0f;
        eabuf[lane] = __expf(u);                 // exp(0)=1 at START, else 0
        __builtin_amdgcn_wave_barrier();

        // distance-4 rotating prefetch; loads unconditional, addresses clamped
        float fr0 = fb[0 * NK], fr1 = fb[1 * NK], fr2 = fb[2 * NK], fr3 = fb[3 * NK];

        auto fstep = [&](float fc) {
            float ea[NK];
            {
                const float4* e4 = (const float4*)eabuf;
                #pragma unroll
                for (int q = 0; q < NK / 4; ++q) {
                    float4 r = e4[q];
                    ea[4 * q + 0] = r.x; ea[4 * q + 1] = r.y;
                    ea[4 * q + 2] = r.z; ea[4 * q + 3] = r.w;
                }
            }
            float a0 = 0.f, a1 = 0.f, a2 = 0.f, a3 = 0.f;
            #pragma unroll
            for (int p = 0; p < NK; p += 4) {
                a0 = fmaf(Erow[p + 0], ea[p + 0], a0);
                a1 = fmaf(Erow[p + 1], ea[p + 1], a1);
                a2 = fmaf(Erow[p + 2], ea[p + 2], a2);
                a3 = fmaf(Erow[p + 3], ea[p + 3], a3);
            }
            float acc = (a0 + a1) + (a2 + a3);   // > 0 always (ea[0]==1, Erow[n][0]>0)
            float w = __logf(acc) + fc;          // lane START: log(0)=-inf, stays -inf
            float dM = rfl_f32(w);               // lane-0 anchor (finite always)
            Muni += dM;
            u = w - dM;                          // u[0] == 0 exactly
            __builtin_amdgcn_wave_barrier();
            eabuf[lane] = __expf(u);
            __builtin_amdgcn_wave_barrier();
        };

        for (int t = 0; t < NT; t += 4) {
            { float fc = fr0; int nr = (t + 4 < NT) ? t + 4 : NT - 1; fr0 = fb[nr * NK]; fstep(fc); }
            { float fc = fr1; int nr = (t + 5 < NT) ? t + 5 : NT - 1; fr1 = fb[nr * NK]; fstep(fc); }
            { float fc = fr2; int nr = (t + 6 < NT) ? t + 6 : NT - 1; fr2 = fb[nr * NK]; fstep(fc); }
            { float fc = fr3; int nr = (t + 7 < NT) ? t + 7 : NT - 1; fr3 = fb[nr * NK]; fstep(fc); }
        }
        // logz = Muni + logsumexp(u + tEnd)
        float x = act ? (u + tEnd) : -INFINITY;
        float M2 = x;
        #pragma unroll
        for (int off = 32; off >= 1; off >>= 1)
            M2 = fmaxf(M2, __shfl_xor(M2, off, 64));
        float e = __expf(x - M2);
        #pragma unroll
        for (int off = 32; off >= 1; off >>= 1)
            e += __shfl_xor(e, off, 64);
        if (lane == 0) out[b] = Muni + M2 + __logf(e);
    } else {
        // ---------------- viterbi: exact fp32, reference op order
        float trow[NK];
        {
            const bool rowdead = (lane == S_START);
            const float4* r4 = (const float4*)(trans + LL * NK);
            #pragma unroll
            for (int q = 0; q < NK / 4; ++q) {
                float4 r = r4[q];
                const int c = 4 * q;
                trow[c + 0] = (rowdead || c + 0 == S_END) ? NEGV : r.x;
                trow[c + 1] = (rowdead || c + 1 == S_END) ? NEGV : r.y;
                trow[c + 2] = (rowdead || c + 2 == S_END) ? NEGV : r.z;
                trow[c + 3] = (rowdead || c + 3 == S_END) ? NEGV : r.w;
            }
        }
        float v = (lane == S_START) ? 0.0f : NEGV;
        vbuf[lane] = v;
        __builtin_amdgcn_wave_barrier();

        float fr0 = fb[0 * NK], fr1 = fb[1 * NK], fr2 = fb[2 * NK], fr3 = fb[3 * NK];
        const int big = 63;

        // REORDERED vstep: the value recurrence (s -> maxtree -> v -> vbuf write)
        // completes FIRST so the next step's 12 ds_read_b128 are queued in the
        // in-order DS pipe as early as possible; the ~120 argmax VALU ops then
        // execute UNDER the read latency instead of extending the critical path.
        auto vstep = [&](float fc, int tt) {
            float s[NK];
            {
                const float4* v4 = (const float4*)vbuf;
                #pragma unroll
                for (int q = 0; q < NK / 4; ++q) {
                    float4 r = v4[q];
                    s[4 * q + 0] = r.x + trow[4 * q + 0];
                    s[4 * q + 1] = r.y + trow[4 * q + 1];
                    s[4 * q + 2] = r.z + trow[4 * q + 2];
                    s[4 * q + 3] = r.w + trow[4 * q + 3];
                }
            }
            // exact max via tree (max is exactly associative; identical to np.max)
            float m16[16];
            #pragma unroll
            for (int i = 0; i < 16; ++i)
                m16[i] = fmaxf(fmaxf(s[3 * i], s[3 * i + 1]), s[3 * i + 2]);
            float m6[6];
            #pragma unroll
            for (int i = 0; i < 5; ++i)
                m6[i] = fmaxf(fmaxf(m16[3 * i], m16[3 * i + 1]), m16[3 * i + 2]);
            m6[5] = m16[15];
            float best = fmaxf(fmaxf(fmaxf(m6[0], m6[1]), m6[2]),
                               fmaxf(fmaxf(m6[3], m6[4]), m6[5]));
            // ---- publish the recurrence value immediately
            v = best + fc;                       // reference order: +feat after argmax
            __builtin_amdgcn_wave_barrier();
            vbuf[lane] = v;
            __builtin_amdgcn_wave_barrier();
            // ---- off-chain: first occurrence of the max == np.argmax
            int ix[NK];
            #pragma unroll
            for (int p = 0; p < NK; ++p)
                ix[p] = (s[p] != best) ? big : p;
            int n16[16];
            #pragma unroll
            for (int i = 0; i < 16; ++i)
                n16[i] = min(min(ix[3 * i], ix[3 * i + 1]), ix[3 * i + 2]);
            int n6[6];
            #pragma unroll
            for (int i = 0; i < 5; ++i)
                n6[i] = min(min(n16[3 * i], n16[3 * i + 1]), n16[3 * i + 2]);
            n6[5] = n16[15];
            int bi = min(min(min(n6[0], n6[1]), n6[2]),
                         min(min(n6[3], n6[4]), n6[5]));

            bp[tt * NK + LL] = (unsigned char)bi; // lanes 47..63: same addr, same value
        };

        for (int t = 0; t < NT; t += 4) {
            { float fc = fr0; int nr = (t + 4 < NT) ? t + 4 : NT - 1; fr0 = fb[nr * NK]; vstep(fc, t + 0); }
            { float fc = fr1; int nr = (t + 5 < NT) ? t + 5 : NT - 1; fr1 = fb[nr * NK]; vstep(fc, t + 1); }
            { float fc = fr2; int nr = (t + 6 < NT) ? t + 6 : NT - 1; fr2 = fb[nr * NK]; vstep(fc, t + 2); }
            { float fc = fr3; int nr = (t + 7 < NT) ? t + 7 : NT - 1; fr3 = fb[nr * NK]; vstep(fc, t + 3); }
        }
        // termination: term = v + trans[END]; first-occurrence argmax
        float xv = act ? (v + tEnd) : -INFINITY;
        int idx = act ? lane : 63;
        float val = xv;
        #pragma unroll
        for (int off = 32; off >= 1; off >>= 1) {
            float ov = __shfl_xor(val, off, 64);
            int   oi = __shfl_xor(idx, off, 64);
            if (ov > val || (ov == val && oi < idx)) { val = ov; idx = oi; }
        }
        if (lane == 0) out[NB + b] = val;
        const int last = idx;

        // ---- chunk-composed backtrace (all intra-wave LDS, in-order DS pipe)
        __builtin_amdgcn_wave_barrier();
        int cur[NK];
        #pragma unroll
        for (int k = 0; k < NK; ++k) cur[k] = k;
        const int tbase = lane * 16;                 // 64 chunks of 16 steps
        for (int i = 15; i >= 0; --i) {
            const int t = tbase + i;
            #pragma unroll
            for (int k = 0; k < NK; ++k) cur[k] = bp[t * NK + cur[k]];
        }
        #pragma unroll
        for (int k = 0; k < NK; ++k) comp[lane * NK + k] = (unsigned char)cur[k];
        __builtin_amdgcn_wave_barrier();

        if (lane == 0) {                             // serial chase over 64 maps
            int tag = last;
            for (int l = 63; l >= 0; --l) {
                boundary[l] = (unsigned char)tag;
                tag = comp[l * NK + tag];
            }
        }
        __builtin_amdgcn_wave_barrier();

        int tag = boundary[lane];
        float* pout = out + 2 * NB + (size_t)b * NT;
        for (int i = 15; i >= 0; --i) {              // re-expand: path[t]=tag, then step
            const int t = tbase + i;
            pout[t] = (float)tag;
            tag = bp[t * NK + tag];
        }
    }
}

extern "C" void kernel_launch(void* const* d_in, const int* in_sizes, int n_in,
                              void* d_out, int out_size, void* d_ws, size_t ws_size,
                              hipStream_t stream) {
    (void)in_sizes; (void)n_in; (void)d_ws; (void)ws_size; (void)out_size;
    const float* feats = (const float*)d_in[0];
    const float* trans = (const float*)d_in[1];
    float* out = (float*)d_out;
    crf_fused<<<dim3(NB), dim3(128), 0, stream>>>(feats, trans, out);
}

// Round 7
// 495.603 us; speedup vs baseline: 1.6285x; 1.0661x over previous
//
#include <hip/hip_runtime.h>

#define NB 512
#define NT 1024
#define NK 48
#define NEGV -10000.0f
#define S_START 46
#define S_END 47
#define NCH 64            // 16-step windows (chunks)
#define CLEN 16

__device__ __forceinline__ float rfl_f32(float x) {
    return __int_as_float(__builtin_amdgcn_readfirstlane(__float_as_int(x)));
}

// 4 waves/block, lockstep-barrier pipeline (66 __syncthreads per wave —
// every wave executes the SAME barrier count; deadlock structurally
// impossible). w0: CRF forward. w1: value-only Viterbi sweep, publishes
// chunk-entry checkpoints to a 4-slot LDS ring. w2/w3: replay chunk c
// (even/odd) over windows c,c+1 with the FULL argmax (bit-identical
// arithmetic -> identical backpointers), write bp + composed maps.
// w1 epilogue: boundary chase + path expansion (R0-verified code).
extern "C" __global__ __launch_bounds__(256, 1)
void crf_fused(const float* __restrict__ feats, const float* __restrict__ trans,
               float* __restrict__ out)
{
    __shared__ unsigned char bp[NT * NK];        // 48 KB backpointers
    __shared__ float ckpt[4 * NK];               // 4-slot chunk-entry ring
    __shared__ unsigned char comp[NCH * NK];     // 3 KB composed chunk maps
    __shared__ unsigned char boundary[NCH];
    __shared__ float eabuf[64];                  // fwd broadcast
    __shared__ float vbuf1[64];                  // sweep broadcast
    __shared__ float vbufw[2][64];               // replay broadcast per wave

    const int b = blockIdx.x;
    const int wave = threadIdx.x >> 6;
    const int lane = threadIdx.x & 63;
    const bool act = lane < NK;
    const int LL = act ? lane : (NK - 1);        // lanes 48..63 mirror 47
    const float* f = feats + (size_t)b * NT * NK;
    const float* fb = f + LL;

    float tEnd = NEGV;
    if (act && lane != S_END) tEnd = trans[S_END * NK + lane];

    if (wave == 0) {
        // ---------------- forward: alpha' = Muni + u; u anchored at lane 0
        float Erow[NK];
        {
            const bool rowdead = (lane == S_START);
            const float4* r4 = (const float4*)(trans + LL * NK);
            #pragma unroll
            for (int q = 0; q < NK / 4; ++q) {
                float4 r = r4[q];
                const int c = 4 * q;
                Erow[c + 0] = (rowdead || c + 0 == S_END) ? 0.0f : __expf(r.x);
                Erow[c + 1] = (rowdead || c + 1 == S_END) ? 0.0f : __expf(r.y);
                Erow[c + 2] = (rowdead || c + 2 == S_END) ? 0.0f : __expf(r.z);
                Erow[c + 3] = (rowdead || c + 3 == S_END) ? 0.0f : __expf(r.w);
            }
        }
        float u = (lane == S_START) ? 0.0f : NEGV;
        float Muni = 0.0f;
        eabuf[lane] = __expf(u);
        __builtin_amdgcn_wave_barrier();
        float fr0 = fb[0 * NK], fr1 = fb[1 * NK], fr2 = fb[2 * NK], fr3 = fb[3 * NK];

        auto fstep = [&](float fc) {
            float ea[NK];
            {
                const float4* e4 = (const float4*)eabuf;
                #pragma unroll
                for (int q = 0; q < NK / 4; ++q) {
                    float4 r = e4[q];
                    ea[4 * q + 0] = r.x; ea[4 * q + 1] = r.y;
                    ea[4 * q + 2] = r.z; ea[4 * q + 3] = r.w;
                }
            }
            float a0 = 0.f, a1 = 0.f, a2 = 0.f, a3 = 0.f;
            #pragma unroll
            for (int p = 0; p < NK; p += 4) {
                a0 = fmaf(Erow[p + 0], ea[p + 0], a0);
                a1 = fmaf(Erow[p + 1], ea[p + 1], a1);
                a2 = fmaf(Erow[p + 2], ea[p + 2], a2);
                a3 = fmaf(Erow[p + 3], ea[p + 3], a3);
            }
            float acc = (a0 + a1) + (a2 + a3);
            float w = __logf(acc) + fc;
            float dM = rfl_f32(w);
            Muni += dM;
            u = w - dM;
            __builtin_amdgcn_wave_barrier();
            eabuf[lane] = __expf(u);
            __builtin_amdgcn_wave_barrier();
        };

        __syncthreads();                                     // B0
        for (int it = 0; it <= NCH; ++it) {
            if (it < NCH) {
                #pragma unroll
                for (int g = 0; g < 4; ++g) {
                    const int t = it * CLEN + 4 * g;
                    { float fc = fr0; int nr = (t + 4 < NT) ? t + 4 : NT - 1; fr0 = fb[nr * NK]; fstep(fc); }
                    { float fc = fr1; int nr = (t + 5 < NT) ? t + 5 : NT - 1; fr1 = fb[nr * NK]; fstep(fc); }
                    { float fc = fr2; int nr = (t + 6 < NT) ? t + 6 : NT - 1; fr2 = fb[nr * NK]; fstep(fc); }
                    { float fc = fr3; int nr = (t + 7 < NT) ? t + 7 : NT - 1; fr3 = fb[nr * NK]; fstep(fc); }
                }
            }
            __syncthreads();                                 // B1..B65
        }
        float x = act ? (u + tEnd) : -INFINITY;
        float M2 = x;
        #pragma unroll
        for (int off = 32; off >= 1; off >>= 1)
            M2 = fmaxf(M2, __shfl_xor(M2, off, 64));
        float e = __expf(x - M2);
        #pragma unroll
        for (int off = 32; off >= 1; off >>= 1)
            e += __shfl_xor(e, off, 64);
        if (lane == 0) out[b] = Muni + M2 + __logf(e);
    } else if (wave == 1) {
        // ---------------- producer: value-only sweep + checkpoint ring
        float trow[NK];
        {
            const bool rowdead = (lane == S_START);
            const float4* r4 = (const float4*)(trans + LL * NK);
            #pragma unroll
            for (int q = 0; q < NK / 4; ++q) {
                float4 r = r4[q];
                const int c = 4 * q;
                trow[c + 0] = (rowdead || c + 0 == S_END) ? NEGV : r.x;
                trow[c + 1] = (rowdead || c + 1 == S_END) ? NEGV : r.y;
                trow[c + 2] = (rowdead || c + 2 == S_END) ? NEGV : r.z;
                trow[c + 3] = (rowdead || c + 3 == S_END) ? NEGV : r.w;
            }
        }
        float v = (lane == S_START) ? 0.0f : NEGV;
        vbuf1[lane] = v;
        if (act) ckpt[0 * NK + lane] = v;                    // chunk-0 entry
        __builtin_amdgcn_wave_barrier();
        float fr0 = fb[0 * NK], fr1 = fb[1 * NK], fr2 = fb[2 * NK], fr3 = fb[3 * NK];

        auto vstep = [&](float fc) {
            float s[NK];
            {
                const float4* v4 = (const float4*)vbuf1;
                #pragma unroll
                for (int q = 0; q < NK / 4; ++q) {
                    float4 r = v4[q];
                    s[4 * q + 0] = r.x + trow[4 * q + 0];
                    s[4 * q + 1] = r.y + trow[4 * q + 1];
                    s[4 * q + 2] = r.z + trow[4 * q + 2];
                    s[4 * q + 3] = r.w + trow[4 * q + 3];
                }
            }
            float m16[16];
            #pragma unroll
            for (int i = 0; i < 16; ++i)
                m16[i] = fmaxf(fmaxf(s[3 * i], s[3 * i + 1]), s[3 * i + 2]);
            float m6[6];
            #pragma unroll
            for (int i = 0; i < 5; ++i)
                m6[i] = fmaxf(fmaxf(m16[3 * i], m16[3 * i + 1]), m16[3 * i + 2]);
            m6[5] = m16[15];
            float best = fmaxf(fmaxf(fmaxf(m6[0], m6[1]), m6[2]),
                               fmaxf(fmaxf(m6[3], m6[4]), m6[5]));
            v = best + fc;                                   // +feat after max
            __builtin_amdgcn_wave_barrier();
            vbuf1[lane] = v;
            __builtin_amdgcn_wave_barrier();
        };

        int last = 0;
        __syncthreads();                                     // B0
        for (int it = 0; it <= NCH; ++it) {
            if (it < NCH) {
                #pragma unroll
                for (int g = 0; g < 4; ++g) {
                    const int t = it * CLEN + 4 * g;
                    { float fc = fr0; int nr = (t + 4 < NT) ? t + 4 : NT - 1; fr0 = fb[nr * NK]; vstep(fc); }
                    { float fc = fr1; int nr = (t + 5 < NT) ? t + 5 : NT - 1; fr1 = fb[nr * NK]; vstep(fc); }
                    { float fc = fr2; int nr = (t + 6 < NT) ? t + 6 : NT - 1; fr2 = fb[nr * NK]; vstep(fc); }
                    { float fc = fr3; int nr = (t + 7 < NT) ? t + 7 : NT - 1; fr3 = fb[nr * NK]; vstep(fc); }
                }
                // v is now the entry state of chunk it+1 -> ring slot
                if (act && it + 1 < NCH) ckpt[((it + 1) & 3) * NK + lane] = v;
            } else {
                // termination: first-occurrence argmax of v + trans[END]
                float xv = act ? (v + tEnd) : -INFINITY;
                int idx = act ? lane : 63;
                float val = xv;
                #pragma unroll
                for (int off = 32; off >= 1; off >>= 1) {
                    float ov = __shfl_xor(val, off, 64);
                    int   oi = __shfl_xor(idx, off, 64);
                    if (ov > val || (ov == val && oi < idx)) { val = ov; idx = oi; }
                }
                if (lane == 0) out[NB + b] = val;
                last = idx;
            }
            __syncthreads();                                 // B1..B65
        }
        // epilogue: chase + expansion (bp/comp complete after final barrier)
        if (lane == 0) {
            int tag = last;
            for (int l = NCH - 1; l >= 0; --l) {
                boundary[l] = (unsigned char)tag;
                tag = comp[l * NK + tag];
            }
        }
        __builtin_amdgcn_wave_barrier();
        int tag = boundary[lane];                            // lane = chunk
        float* pout = out + 2 * NB + (size_t)b * NT;
        const int tbase = lane * CLEN;
        for (int i = CLEN - 1; i >= 0; --i) {
            pout[tbase + i] = (float)tag;
            tag = bp[(tbase + i) * NK + tag];
        }
    } else {
        // ---------------- consumers: replay chunk c over windows c, c+1
        const int w = wave - 2;                              // 0: even, 1: odd
        float trow[NK];
        {
            const bool rowdead = (lane == S_START);
            const float4* r4 = (const float4*)(trans + LL * NK);
            #pragma unroll
            for (int q = 0; q < NK / 4; ++q) {
                float4 r = r4[q];
                const int c = 4 * q;
                trow[c + 0] = (rowdead || c + 0 == S_END) ? NEGV : r.x;
                trow[c + 1] = (rowdead || c + 1 == S_END) ? NEGV : r.y;
                trow[c + 2] = (rowdead || c + 2 == S_END) ? NEGV : r.z;
                trow[c + 3] = (rowdead || c + 3 == S_END) ? NEGV : r.w;
            }
        }
        float* vbw = vbufw[w];
        const int big = 63;
        int bpl[8], bph[8];

        // 8 replay steps [base, base+8) of chunk c; bparr8 statically indexed
        auto replay8 = [&](int c, int base, int* bparr8) {
            const float* fbc = fb + (size_t)c * CLEN * NK;
            unsigned char* bpc = bp + (size_t)c * CLEN * NK;
            float fv[8];
            #pragma unroll
            for (int i = 0; i < 8; ++i) fv[i] = fbc[(base + i) * NK];
            #pragma unroll
            for (int i = 0; i < 8; ++i) {
                float s[NK];
                {
                    const float4* v4 = (const float4*)vbw;
                    #pragma unroll
                    for (int q = 0; q < NK / 4; ++q) {
                        float4 r = v4[q];
                        s[4 * q + 0] = r.x + trow[4 * q + 0];
                        s[4 * q + 1] = r.y + trow[4 * q + 1];
                        s[4 * q + 2] = r.z + trow[4 * q + 2];
                        s[4 * q + 3] = r.w + trow[4 * q + 3];
                    }
                }
                float m16[16];
                #pragma unroll
                for (int j = 0; j < 16; ++j)
                    m16[j] = fmaxf(fmaxf(s[3 * j], s[3 * j + 1]), s[3 * j + 2]);
                float m6[6];
                #pragma unroll
                for (int j = 0; j < 5; ++j)
                    m6[j] = fmaxf(fmaxf(m16[3 * j], m16[3 * j + 1]), m16[3 * j + 2]);
                m6[5] = m16[15];
                float best = fmaxf(fmaxf(fmaxf(m6[0], m6[1]), m6[2]),
                                   fmaxf(fmaxf(m6[3], m6[4]), m6[5]));
                int ix[NK];
                #pragma unroll
                for (int p = 0; p < NK; ++p)
                    ix[p] = (s[p] != best) ? big : p;
                int n16[16];
                #pragma unroll
                for (int j = 0; j < 16; ++j)
                    n16[j] = min(min(ix[3 * j], ix[3 * j + 1]), ix[3 * j + 2]);
                int n6[6];
                #pragma unroll
                for (int j = 0; j < 5; ++j)
                    n6[j] = min(min(n16[3 * j], n16[3 * j + 1]), n16[3 * j + 2]);
                n6[5] = n16[15];
                int bi = min(min(min(n6[0], n6[1]), n6[2]),
                             min(min(n6[3], n6[4]), n6[5]));

                bparr8[i] = bi;
                bpc[(base + i) * NK + LL] = (unsigned char)bi;
                float vn = best + fv[i];                     // +feat after argmax
                __builtin_amdgcn_wave_barrier();
                vbw[lane] = vn;
                __builtin_amdgcn_wave_barrier();
            }
        };

        __syncthreads();                                     // B0
        for (int it = 0; it <= NCH; ++it) {
            if ((it & 1) == w && it < NCH) {
                // start chunk c = it (ckpt[c] published during window it-1)
                vbw[lane] = ckpt[(it & 3) * NK + LL];
                __builtin_amdgcn_wave_barrier();
                replay8(it, 0, bpl);
            } else if ((it & 1) != w && it >= 1) {
                // finish chunk c = it-1, then compose its tag-map
                const int c = it - 1;
                replay8(c, 8, bph);
                int tag = act ? lane : 0;
                #pragma unroll
                for (int i = 7; i >= 0; --i)
                    tag = __builtin_amdgcn_ds_bpermute(tag << 2, bph[i]);
                #pragma unroll
                for (int i = 7; i >= 0; --i)
                    tag = __builtin_amdgcn_ds_bpermute(tag << 2, bpl[i]);
                if (act) comp[c * NK + lane] = (unsigned char)tag;
            }
            __syncthreads();                                 // B1..B65
        }
    }
}

extern "C" void kernel_launch(void* const* d_in, const int* in_sizes, int n_in,
                              void* d_out, int out_size, void* d_ws, size_t ws_size,
                              hipStream_t stream) {
    (void)in_sizes; (void)n_in; (void)d_ws; (void)ws_size; (void)out_size;
    const float* feats = (const float*)d_in[0];
    const float* trans = (const float*)d_in[1];
    float* out = (float*)d_out;
    crf_fused<<<dim3(NB), dim3(256), 0, stream>>>(feats, trans, out);
}